// Round 15
// baseline (994.988 us; speedup 1.0000x reference)
//
#include <hip/hip_runtime.h>
#include <hip/hip_bf16.h>
#include <math.h>

#define DD   512
#define HN   8
#define DHD  64
#define LL   6
#define DFF_ 2048
#define VV   256
#define KB_  5
#define PP   2048
#define EPS_ 1e-5f
#define TAU_ 0.1f
#define NS   8               // KV splits for flash attention (was 4)
#define KVS  (PP / NS)       // 256 keys per split
#define KSP  2               // split-K for small GEMMs
#define QSCALE 0.18033688f   // 0.125 * log2(e)
#define THRL2  11.5416f

typedef __attribute__((ext_vector_type(8))) short bf16x8;
typedef __attribute__((ext_vector_type(4))) short bf16x4;
typedef __attribute__((ext_vector_type(4))) float f32x4;

// ---------------- helpers ----------------
__device__ __forceinline__ float wave_sum(float v) {
#pragma unroll
  for (int m = 32; m >= 1; m >>= 1) v += __shfl_xor(v, m, 64);
  return v;
}

__device__ __forceinline__ unsigned short f2bf(float f) {
  unsigned u = __float_as_uint(f);
  u += 0x7FFF + ((u >> 16) & 1);
  return (unsigned short)(u >> 16);
}

__device__ __forceinline__ float bf2f(unsigned short u) {
  return __uint_as_float(((unsigned)u) << 16);
}

__device__ __forceinline__ bf16x8 cvt8(float4 a, float4 b) {
  bf16x8 v;
  v[0] = (short)f2bf(a.x); v[1] = (short)f2bf(a.y);
  v[2] = (short)f2bf(a.z); v[3] = (short)f2bf(a.w);
  v[4] = (short)f2bf(b.x); v[5] = (short)f2bf(b.y);
  v[6] = (short)f2bf(b.z); v[7] = (short)f2bf(b.w);
  return v;
}

__device__ __forceinline__ void gload16(const void* g, void* l) {
  __builtin_amdgcn_global_load_lds(
      (const __attribute__((address_space(1))) unsigned int*)g,
      (__attribute__((address_space(3))) unsigned int*)l, 16, 0, 0);
}

// ---------------- batched fp32 -> bf16 convert ----------------
#define NSEG 55
struct CvtSeg { const float* src; short* dst; int n; };
struct CvtArgs { CvtSeg seg[NSEG]; };

__global__ __launch_bounds__(256) void convert_bf16_kernel(CvtArgs a) {
  const CvtSeg sg = a.seg[blockIdx.y];
  const int i = ((int)blockIdx.x * 256 + (int)threadIdx.x) * 16;
  if (i >= sg.n) return;
  const float4 x0 = *(const float4*)(sg.src + i);
  const float4 x1 = *(const float4*)(sg.src + i + 4);
  const float4 x2 = *(const float4*)(sg.src + i + 8);
  const float4 x3 = *(const float4*)(sg.src + i + 12);
  *(bf16x8*)(sg.dst + i)     = cvt8(x0, x1);
  *(bf16x8*)(sg.dst + i + 8) = cvt8(x2, x3);
}

// ---------------- Wv transpose+convert ----------------
__global__ __launch_bounds__(256) void transpose_wv_kernel(const float* __restrict__ sa_inw,
                                                           short* __restrict__ wvt) {
  __shared__ float t[64][65];
  const int l = blockIdx.z;
  const float* S = sa_inw + (size_t)l * 3 * DD * DD + (size_t)2 * DD * DD;
  short* D = wvt + (size_t)l * DD * DD;
  const int bo = blockIdx.y * 64;
  const int bi = blockIdx.x * 64;
  const int r = (int)threadIdx.x >> 2;
  const int c0 = ((int)threadIdx.x & 3) * 16;
#pragma unroll
  for (int j = 0; j < 16; j += 4)
    *(float4*)&t[r][c0 + j] = *(const float4*)&S[(size_t)(bo + r) * DD + bi + c0 + j];
  __syncthreads();
  bf16x8 o0, o1;
#pragma unroll
  for (int j = 0; j < 8; ++j) o0[j] = (short)f2bf(t[c0 + j][r]);
#pragma unroll
  for (int j = 0; j < 8; ++j) o1[j] = (short)f2bf(t[c0 + 8 + j][r]);
  short* dp = &D[(size_t)(bi + r) * DD + bo + c0];
  *(bf16x8*)dp = o0;
  *(bf16x8*)(dp + 8) = o1;
}

// ---------------- sa bias combine ----------------
__global__ __launch_bounds__(256) void sa_bias_kernel(const float* __restrict__ sa_inb,
                                                      const float* __restrict__ sa_ow,
                                                      const float* __restrict__ sa_ob,
                                                      float* __restrict__ bc) {
  const int gid = (int)blockIdx.x * 4 + ((int)threadIdx.x >> 6);
  const int l = gid >> 9, n = gid & 511;
  const int lane = (int)threadIdx.x & 63;
  const float* wo = sa_ow + (size_t)l * DD * DD + (size_t)n * DD + lane * 8;
  const float* bv = sa_inb + (size_t)l * 3 * DD + 2 * DD + lane * 8;
  float s = 0.f;
#pragma unroll
  for (int j = 0; j < 8; ++j) s += wo[j] * bv[j];
  s = wave_sum(s);
  if (lane == 0) bc[(size_t)l * DD + n] = s + sa_ob[(size_t)l * DD + n];
}

// ---------------- batched Wc = Wo @ Wv, 6 layers (BK=64) ----------------
__global__ __launch_bounds__(256) void gemm_wc_kernel(const short* __restrict__ WoBase,
                                                      size_t astr,
                                                      const short* __restrict__ WvT,
                                                      short* __restrict__ Wc) {
  constexpr int BK = 64;
  __shared__ short As[64 * BK];
  __shared__ short Bs[64 * BK];
  const int l = blockIdx.z;
  const short* A = WoBase + (size_t)l * astr;
  const short* W = WvT + (size_t)l * DD * DD;
  short* C = Wc + (size_t)l * DD * DD;
  const int tid = (int)threadIdx.x;
  const int lane = tid & 63;
  const int wid = tid >> 6;
  const int wm = (wid >> 1) * 32;
  const int wn = (wid & 1) * 32;
  const int bm = blockIdx.y * 64;
  const int bn = blockIdx.x * 64;
  const int fr = lane & 15;
  const int kq = lane >> 4;
  const int rs = fr & 7;
  const int srow = lane >> 3;
  const int scg = (lane & 7) ^ srow;

  f32x4 acc[2][2];
#pragma unroll
  for (int i = 0; i < 2; ++i)
#pragma unroll
    for (int j = 0; j < 2; ++j) acc[i][j] = (f32x4){0.f, 0.f, 0.f, 0.f};

  for (int k0 = 0; k0 < DD; k0 += BK) {
    __syncthreads();
#pragma unroll
    for (int is = 0; is < 2; ++is) {
      const int ib = is * 4 + wid;
      gload16(&A[(size_t)(bm + ib * 8 + srow) * DD + k0 + scg * 8], &As[ib * 512]);
      gload16(&W[(size_t)(bn + ib * 8 + srow) * DD + k0 + scg * 8], &Bs[ib * 512]);
    }
    __syncthreads();
#pragma unroll
    for (int s = 0; s < 2; ++s) {
      const int cg = s * 4 + kq;
      const int co = (cg ^ rs) * 8;
      bf16x8 af[2], bf[2];
#pragma unroll
      for (int i = 0; i < 2; ++i) af[i] = *(const bf16x8*)&As[(wm + i * 16 + fr) * BK + co];
#pragma unroll
      for (int j = 0; j < 2; ++j) bf[j] = *(const bf16x8*)&Bs[(wn + j * 16 + fr) * BK + co];
#pragma unroll
      for (int i = 0; i < 2; ++i)
#pragma unroll
        for (int j = 0; j < 2; ++j)
          acc[i][j] = __builtin_amdgcn_mfma_f32_16x16x32_bf16(af[i], bf[j], acc[i][j], 0, 0, 0);
    }
  }
  const int cr = (lane >> 4) * 4;
#pragma unroll
  for (int j = 0; j < 2; ++j) {
    const int col = bn + wn + j * 16 + fr;
#pragma unroll
    for (int i = 0; i < 2; ++i)
#pragma unroll
      for (int r = 0; r < 4; ++r)
        C[(size_t)(bm + wm + i * 16 + cr + r) * DD + col] = (short)f2bf(acc[i][j][r]);
  }
}

// ---------------- embedding (bf16 x master) ----------------
__global__ __launch_bounds__(256) void embed_mean_kernel(const int* __restrict__ bytes,
                                                         const float* __restrict__ emb,
                                                         short* __restrict__ xb,
                                                         float* __restrict__ tok) {
  const int p = blockIdx.x;
  const int d = threadIdx.x * 2;
  float a0 = 0.f, a1 = 0.f;
  int last = 0;
#pragma unroll
  for (int k = 0; k < KB_; ++k) {
    const int idx = bytes[p * KB_ + k];
    last = idx;
    const float* e = emb + (size_t)idx * DD + d;
    a0 += e[0]; a1 += e[1];
  }
  xb[(size_t)p * DD + d]     = (short)f2bf(a0 * 0.2f);
  xb[(size_t)p * DD + d + 1] = (short)f2bf(a1 * 0.2f);
  const float* e = emb + (size_t)last * DD + d;
  tok[(size_t)p * DD + d]     = e[0];
  tok[(size_t)p * DD + d + 1] = e[1];
}

// ---------------- MFMA GEMM, BK=128, gload_lds + XOR swizzle ----------------
template <int BM, int BN, int NSPLIT, int RELU, int WF32, int WBF16, int QS>
__global__ __launch_bounds__(256) void gemm_gl_kernel(
    const short* __restrict__ A, int lda,
    const short* __restrict__ W, int ldw,
    const float* __restrict__ bias,
    float* __restrict__ Cf, short* __restrict__ Cb, int ldc, int Kd,
    size_t pstride) {
  constexpr int BK = 128;
  __shared__ short As[BM * BK];
  __shared__ short Bs[BN * BK];
  constexpr int WM = BM / 2, WN = BN / 2;
  constexpr int MF = WM / 16, NF = WN / 16;
  const int tid = (int)threadIdx.x;
  const int lane = tid & 63;
  const int wid = tid >> 6;
  const int wm = (wid >> 1) * WM;
  const int wn = (wid & 1) * WN;
  const int bm = blockIdx.y * BM;
  const int bn = blockIdx.x * BN;
  const int fr = lane & 15;
  const int kq = lane >> 4;
  const int srow = lane >> 4;
  const int sc16 = lane & 15;

  const int kz = (NSPLIT > 1) ? (int)blockIdx.z : 0;
  const int kbeg = kz * (Kd / NSPLIT);
  const int kend = kbeg + Kd / NSPLIT;

  f32x4 acc[MF][NF];
#pragma unroll
  for (int i = 0; i < MF; ++i)
#pragma unroll
    for (int j = 0; j < NF; ++j) acc[i][j] = (f32x4){0.f, 0.f, 0.f, 0.f};

  for (int k0 = kbeg; k0 < kend; k0 += BK) {
    __syncthreads();
#pragma unroll
    for (int is = 0; is < BM / 16; ++is) {
      const int ib = is * 4 + wid;
      const int row = ib * 4 + srow;
      const int cg = sc16 ^ (row & 15);
      gload16(&A[(size_t)(bm + row) * lda + k0 + cg * 8], &As[ib * 512]);
    }
#pragma unroll
    for (int is = 0; is < BN / 16; ++is) {
      const int ib = is * 4 + wid;
      const int row = ib * 4 + srow;
      const int cg = sc16 ^ (row & 15);
      gload16(&W[(size_t)(bn + row) * ldw + k0 + cg * 8], &Bs[ib * 512]);
    }
    __syncthreads();
#pragma unroll
    for (int s = 0; s < 4; ++s) {
      const int co = ((s * 4 + kq) ^ fr) * 8;
      bf16x8 af[MF], bf[NF];
#pragma unroll
      for (int i = 0; i < MF; ++i)
        af[i] = *(const bf16x8*)&As[(wm + i * 16 + fr) * BK + co];
#pragma unroll
      for (int j = 0; j < NF; ++j)
        bf[j] = *(const bf16x8*)&Bs[(wn + j * 16 + fr) * BK + co];
#pragma unroll
      for (int i = 0; i < MF; ++i)
#pragma unroll
        for (int j = 0; j < NF; ++j)
          acc[i][j] = __builtin_amdgcn_mfma_f32_16x16x32_bf16(af[i], bf[j], acc[i][j], 0, 0, 0);
    }
  }

  const int cr = (lane >> 4) * 4;
  if constexpr (NSPLIT > 1) {
#pragma unroll
    for (int j = 0; j < NF; ++j) {
      const int col = bn + wn + j * 16 + fr;
#pragma unroll
      for (int i = 0; i < MF; ++i)
#pragma unroll
        for (int r = 0; r < 4; ++r) {
          const size_t idx = (size_t)(bm + wm + i * 16 + cr + r) * ldc + col;
          if (WF32) Cf[(size_t)kz * pstride + idx] = acc[i][j][r];
          else      Cb[(size_t)kz * pstride + idx] = (short)f2bf(acc[i][j][r]);
        }
    }
  } else {
#pragma unroll
    for (int j = 0; j < NF; ++j) {
      const int col = bn + wn + j * 16 + fr;
      const float bb = bias[col];
      const float sc = (QS && col < DD) ? QSCALE : 1.f;
#pragma unroll
      for (int i = 0; i < MF; ++i) {
#pragma unroll
        for (int r = 0; r < 4; ++r) {
          float v = (acc[i][j][r] + bb) * sc;
          if (RELU) v = fmaxf(v, 0.f);
          const size_t idx = (size_t)(bm + wm + i * 16 + cr + r) * ldc + col;
          if (WF32) Cf[idx] = v;
          if (WBF16) Cb[idx] = (short)f2bf(v);
        }
      }
    }
  }
}

// ---------------- merged decoder cross-attn projections, BK=128 ----------------
__global__ __launch_bounds__(256) void gemm_ca_kernel(
    const short* __restrict__ Aq, const short* __restrict__ Akv,
    const short* __restrict__ Wfull, const float* __restrict__ bias,
    short* __restrict__ Cb) {
  constexpr int BK = 128;
  __shared__ short As[64 * BK];
  __shared__ short Bs[64 * BK];
  const int bx = (int)blockIdx.x;
  const int part_kv = bx >= 8;
  const short* A = part_kv ? Akv : Aq;
  const int wrow0 = part_kv ? DD + (bx - 8) * 64 : bx * 64;
  const float sc = part_kv ? 1.f : QSCALE;
  const int tid = (int)threadIdx.x;
  const int lane = tid & 63;
  const int wid = tid >> 6;
  const int wm = (wid >> 1) * 32;
  const int wn = (wid & 1) * 32;
  const int bm = blockIdx.y * 64;
  const int fr = lane & 15;
  const int kq = lane >> 4;
  const int srow = lane >> 4;
  const int sc16 = lane & 15;

  f32x4 acc[2][2];
#pragma unroll
  for (int i = 0; i < 2; ++i)
#pragma unroll
    for (int j = 0; j < 2; ++j) acc[i][j] = (f32x4){0.f, 0.f, 0.f, 0.f};

  for (int k0 = 0; k0 < DD; k0 += BK) {
    __syncthreads();
#pragma unroll
    for (int is = 0; is < 4; ++is) {
      const int ib = is * 4 + wid;
      const int row = ib * 4 + srow;
      const int cg = sc16 ^ (row & 15);
      gload16(&A[(size_t)(bm + row) * DD + k0 + cg * 8], &As[ib * 512]);
    }
#pragma unroll
    for (int is = 0; is < 4; ++is) {
      const int ib = is * 4 + wid;
      const int row = ib * 4 + srow;
      const int cg = sc16 ^ (row & 15);
      gload16(&Wfull[(size_t)(wrow0 + row) * DD + k0 + cg * 8], &Bs[ib * 512]);
    }
    __syncthreads();
#pragma unroll
    for (int s = 0; s < 4; ++s) {
      const int co = ((s * 4 + kq) ^ fr) * 8;
      bf16x8 af[2], bf[2];
#pragma unroll
      for (int i = 0; i < 2; ++i) af[i] = *(const bf16x8*)&As[(wm + i * 16 + fr) * BK + co];
#pragma unroll
      for (int j = 0; j < 2; ++j) bf[j] = *(const bf16x8*)&Bs[(wn + j * 16 + fr) * BK + co];
#pragma unroll
      for (int i = 0; i < 2; ++i)
#pragma unroll
        for (int j = 0; j < 2; ++j)
          acc[i][j] = __builtin_amdgcn_mfma_f32_16x16x32_bf16(af[i], bf[j], acc[i][j], 0, 0, 0);
    }
  }
  const int cr = (lane >> 4) * 4;
#pragma unroll
  for (int j = 0; j < 2; ++j) {
    const int col = wrow0 + wn + j * 16 + fr;
    const float bb = bias[col];
#pragma unroll
    for (int i = 0; i < 2; ++i)
#pragma unroll
      for (int r = 0; r < 4; ++r)
        Cb[(size_t)(bm + wm + i * 16 + cr + r) * (3 * DD) + col] =
            (short)f2bf((acc[i][j][r] + bb) * sc);
  }
}

// ---------------- MFMA flash attention (swapped QK^T, exp2, defer-max) ----------------
__global__ __launch_bounds__(256) void flash_attn_mfma_kernel(const short* __restrict__ qkvb,
                                                              short* __restrict__ Opart,
                                                              float* __restrict__ stats) {
  constexpr int LS = 72;
  __shared__ short Ks[64 * 64];
  __shared__ short Vt[64 * LS];
  __shared__ short Ps[64 * LS];
  const int h = blockIdx.y;
  const int q0 = blockIdx.x * 64;
  const int sp = blockIdx.z;
  const int tid = (int)threadIdx.x;
  const int lane = tid & 63;
  const int wid = tid >> 6;
  const int fr = lane & 15;
  const int g = lane >> 4;
  const int kg = g * 8;
  const int rs3 = fr & 7;

  bf16x8 qf[2];
  {
    const short* src = qkvb + (size_t)(q0 + wid * 16 + fr) * (3 * DD) + h * DHD + kg;
    qf[0] = *(const bf16x8*)src;
    qf[1] = *(const bf16x8*)(src + 32);
  }

  f32x4 acc_o[4];
#pragma unroll
  for (int df = 0; df < 4; ++df) acc_o[df] = (f32x4){0.f, 0.f, 0.f, 0.f};
  float mreg = -INFINITY, lsum = 0.f;

  const int srow8 = lane >> 3;
  const int sscg = (lane & 7) ^ srow8;
  const int vk2 = (tid & 31) * 2;
  const int vd8 = (tid >> 5) * 8;

  for (int t = 0; t < KVS / 64; ++t) {
    const int k0 = sp * KVS + t * 64;
    __syncthreads();
    {
#pragma unroll
      for (int p = 0; p < 2; ++p) {
        const int rb = p * 32 + wid * 8;
        gload16(&qkvb[(size_t)(k0 + rb + srow8) * (3 * DD) + DD + h * DHD + sscg * 8],
                &Ks[rb * 64]);
      }
      const short* vbase = qkvb + (size_t)(k0 + vk2) * (3 * DD) + 2 * DD + h * DHD + vd8;
      const bf16x8 v0 = *(const bf16x8*)vbase;
      const bf16x8 v1 = *(const bf16x8*)(vbase + 3 * DD);
#pragma unroll
      for (int j = 0; j < 8; ++j) {
        const unsigned pk = ((unsigned)(unsigned short)v0[j]) |
                            (((unsigned)(unsigned short)v1[j]) << 16);
        *(unsigned*)&Vt[(vd8 + j) * LS + vk2] = pk;
      }
    }
    __syncthreads();

    f32x4 st[4];
#pragma unroll
    for (int nf = 0; nf < 4; ++nf) st[nf] = (f32x4){0.f, 0.f, 0.f, 0.f};
    __builtin_amdgcn_s_setprio(1);
#pragma unroll
    for (int nf = 0; nf < 4; ++nf) {
      const int krow = (nf * 16 + fr) * 64;
      const bf16x8 kf0 = *(const bf16x8*)&Ks[krow + ((g ^ rs3) * 8)];
      const bf16x8 kf1 = *(const bf16x8*)&Ks[krow + (((g + 4) ^ rs3) * 8)];
      st[nf] = __builtin_amdgcn_mfma_f32_16x16x32_bf16(kf0, qf[0], st[nf], 0, 0, 0);
      st[nf] = __builtin_amdgcn_mfma_f32_16x16x32_bf16(kf1, qf[1], st[nf], 0, 0, 0);
    }
    __builtin_amdgcn_s_setprio(0);

    float mx = st[0][0];
#pragma unroll
    for (int nf = 0; nf < 4; ++nf)
#pragma unroll
      for (int i = 0; i < 4; ++i) mx = fmaxf(mx, st[nf][i]);
    mx = fmaxf(mx, __shfl_xor(mx, 16, 64));
    mx = fmaxf(mx, __shfl_xor(mx, 32, 64));

    if (!__all(mx <= mreg + THRL2)) {
      const float mn = fmaxf(mreg, mx);
      const float corr = exp2f(mreg - mn);
      mreg = mn;
      lsum *= corr;
      float corr_acc[4];
#pragma unroll
      for (int i = 0; i < 4; ++i)
        corr_acc[i] = __shfl(corr, (lane & 48) | (g * 4 + i), 64);
#pragma unroll
      for (int df = 0; df < 4; ++df) {
        acc_o[df][0] *= corr_acc[0]; acc_o[df][1] *= corr_acc[1];
        acc_o[df][2] *= corr_acc[2]; acc_o[df][3] *= corr_acc[3];
      }
    }

    float pv[4][4];
    float sum = 0.f;
#pragma unroll
    for (int nf = 0; nf < 4; ++nf)
#pragma unroll
      for (int i = 0; i < 4; ++i) {
        pv[nf][i] = exp2f(st[nf][i] - mreg);
        sum += pv[nf][i];
      }
    sum += __shfl_xor(sum, 16, 64);
    sum += __shfl_xor(sum, 32, 64);
    lsum += sum;

#pragma unroll
    for (int nf = 0; nf < 4; ++nf) {
      bf16x4 pw;
#pragma unroll
      for (int i = 0; i < 4; ++i) pw[i] = (short)f2bf(pv[nf][i]);
      *(bf16x4*)&Ps[(wid * 16 + fr) * LS + nf * 16 + g * 4] = pw;
    }
    asm volatile("s_waitcnt lgkmcnt(0)" ::: "memory");

    const bf16x8 pa0 = *(const bf16x8*)&Ps[(wid * 16 + fr) * LS + kg];
    const bf16x8 pa1 = *(const bf16x8*)&Ps[(wid * 16 + fr) * LS + kg + 32];
    __builtin_amdgcn_s_setprio(1);
#pragma unroll
    for (int df = 0; df < 4; ++df) {
      const bf16x8 vb0 = *(const bf16x8*)&Vt[(df * 16 + fr) * LS + kg];
      const bf16x8 vb1 = *(const bf16x8*)&Vt[(df * 16 + fr) * LS + kg + 32];
      acc_o[df] = __builtin_amdgcn_mfma_f32_16x16x32_bf16(pa0, vb0, acc_o[df], 0, 0, 0);
      acc_o[df] = __builtin_amdgcn_mfma_f32_16x16x32_bf16(pa1, vb1, acc_o[df], 0, 0, 0);
    }
    __builtin_amdgcn_s_setprio(0);
  }

  const int orow = q0 + wid * 16 + g * 4;
#pragma unroll
  for (int df = 0; df < 4; ++df)
#pragma unroll
    for (int i = 0; i < 4; ++i)
      Opart[((size_t)sp * PP + orow + i) * DD + h * DHD + df * 16 + fr] =
          (short)f2bf(acc_o[df][i]);
  if (g == 0) {
    const size_t si = (((size_t)sp * PP + q0 + wid * 16 + fr) * HN + h) * 2;
    stats[si]     = mreg;
    stats[si + 1] = lsum;
  }
}

// ---------------- combine NS bf16 partials -> attno bf16 ----------------
__global__ __launch_bounds__(256) void attn_combine_kernel(const short* __restrict__ Opart,
                                                           const float* __restrict__ stats,
                                                           short* __restrict__ outb) {
  const int row = blockIdx.x * 4 + ((int)threadIdx.x >> 6);
  const int lane = (int)threadIdx.x & 63;
  const int d0 = lane * 8;
  const int h = d0 >> 6;
  float m[NS], l[NS];
  float M = -INFINITY;
#pragma unroll
  for (int s = 0; s < NS; ++s) {
    const size_t si = (((size_t)s * PP + row) * HN + h) * 2;
    m[s] = stats[si]; l[s] = stats[si + 1];
    M = fmaxf(M, m[s]);
  }
  float L = 0.f;
  float o[8];
#pragma unroll
  for (int j = 0; j < 8; ++j) o[j] = 0.f;
#pragma unroll
  for (int s = 0; s < NS; ++s) {
    const float e = exp2f(m[s] - M);
    L += l[s] * e;
    const bf16x8 v = *(const bf16x8*)&Opart[((size_t)s * PP + row) * DD + d0];
#pragma unroll
    for (int j = 0; j < 8; ++j) o[j] += bf2f((unsigned short)v[j]) * e;
  }
  const float inv = 1.f / L;
  bf16x8 ob;
#pragma unroll
  for (int j = 0; j < 8; ++j) ob[j] = (short)f2bf(o[j] * inv);
  *(bf16x8*)&outb[(size_t)row * DD + d0] = ob;
}

// ---------------- LN(x + ΣP + gbias) * w + b -> bf16 ----------------
__global__ __launch_bounds__(256) void ln_residual_kernel(const short* __restrict__ xin,
                                                          const short* __restrict__ pP,
                                                          size_t pstride,
                                                          const float* __restrict__ gb,
                                                          const float* __restrict__ w,
                                                          const float* __restrict__ b,
                                                          short* __restrict__ outb) {
  const int row = blockIdx.x * 4 + (threadIdx.x >> 6);
  const int lane = threadIdx.x & 63;
  const size_t base = (size_t)row * DD + lane * 8;
  float v[8];
  {
    const bf16x8 a = *(const bf16x8*)&xin[base];
    const float4 g0 = *(const float4*)&gb[lane * 8];
    const float4 g1 = *(const float4*)&gb[lane * 8 + 4];
    const float gg[8] = {g0.x, g0.y, g0.z, g0.w, g1.x, g1.y, g1.z, g1.w};
#pragma unroll
    for (int j = 0; j < 8; ++j) v[j] = bf2f((unsigned short)a[j]) + gg[j];
#pragma unroll
    for (int s = 0; s < KSP; ++s) {
      const bf16x8 p = *(const bf16x8*)&pP[s * pstride + base];
#pragma unroll
      for (int j = 0; j < 8; ++j) v[j] += bf2f((unsigned short)p[j]);
    }
  }
  float sum = 0.f;
#pragma unroll
  for (int j = 0; j < 8; ++j) sum += v[j];
  sum = wave_sum(sum);
  const float mean = sum * (1.f / DD);
  float sq = 0.f;
#pragma unroll
  for (int j = 0; j < 8; ++j) { const float dd = v[j] - mean; sq += dd * dd; }
  sq = wave_sum(sq);
  const float rstd = rsqrtf(sq * (1.f / DD) + EPS_);
  const float* wp = w + lane * 8;
  const float* bp = b + lane * 8;
  bf16x8 ob;
#pragma unroll
  for (int j = 0; j < 8; ++j)
    ob[j] = (short)f2bf((v[j] - mean) * rstd * wp[j] + bp[j]);
  *(bf16x8*)&outb[base] = ob;
}

// ---------------- final encoder LN fused with gate+mix ----------------
__global__ __launch_bounds__(256) void ln_gate_kernel(const short* __restrict__ xin,
                                                      const short* __restrict__ pP,
                                                      size_t pstride,
                                                      const float* __restrict__ gb,
                                                      const float* __restrict__ w,
                                                      const float* __restrict__ b,
                                                      const float* __restrict__ tok,
                                                      const float* __restrict__ alpha_p,
                                                      short* __restrict__ xb,
                                                      short* __restrict__ encb) {
  const int row = blockIdx.x * 4 + (threadIdx.x >> 6);
  const int lane = threadIdx.x & 63;
  const size_t base = (size_t)row * DD + lane * 8;
  float v[8];
  {
    const bf16x8 a = *(const bf16x8*)&xin[base];
    const float4 g0 = *(const float4*)&gb[lane * 8];
    const float4 g1 = *(const float4*)&gb[lane * 8 + 4];
    const float gg[8] = {g0.x, g0.y, g0.z, g0.w, g1.x, g1.y, g1.z, g1.w};
#pragma unroll
    for (int j = 0; j < 8; ++j) v[j] = bf2f((unsigned short)a[j]) + gg[j];
#pragma unroll
    for (int s = 0; s < KSP; ++s) {
      const bf16x8 p = *(const bf16x8*)&pP[s * pstride + base];
#pragma unroll
      for (int j = 0; j < 8; ++j) v[j] += bf2f((unsigned short)p[j]);
    }
  }
  float sum = 0.f;
#pragma unroll
  for (int j = 0; j < 8; ++j) sum += v[j];
  sum = wave_sum(sum);
  const float mean = sum * (1.f / DD);
  float sq = 0.f;
#pragma unroll
  for (int j = 0; j < 8; ++j) { const float dd = v[j] - mean; sq += dd * dd; }
  sq = wave_sum(sq);
  const float rstd = rsqrtf(sq * (1.f / DD) + EPS_);
  const float* wp = w + lane * 8;
  const float* bp = b + lane * 8;
  float e[8];
#pragma unroll
  for (int j = 0; j < 8; ++j) e[j] = (v[j] - mean) * rstd * wp[j] + bp[j];
  bf16x8 eb;
#pragma unroll
  for (int j = 0; j < 8; ++j) eb[j] = (short)f2bf(e[j]);
  *(bf16x8*)&encb[base] = eb;
  float nsq = 0.f;
#pragma unroll
  for (int j = 0; j < 8; ++j) nsq += e[j] * e[j];
  nsq = wave_sum(nsq);
  const bool gate = nsq > TAU_ * TAU_;
  const float a = *alpha_p;
  float t[8];
  {
    const float4 b0 = *(const float4*)&tok[base];
    const float4 b1 = *(const float4*)&tok[base + 4];
    t[0] = b0.x; t[1] = b0.y; t[2] = b0.z; t[3] = b0.w;
    t[4] = b1.x; t[5] = b1.y; t[6] = b1.z; t[7] = b1.w;
  }
  bf16x8 ob;
#pragma unroll
  for (int j = 0; j < 8; ++j)
    ob[j] = (short)f2bf(gate ? (a * e[j] + (1.f - a) * t[j]) : t[j]);
  *(bf16x8*)&xb[base] = ob;
}

// ---------------- final out combine: d_out = ΣP + bias ----------------
__global__ __launch_bounds__(256) void out_combine_kernel(const float* __restrict__ P,
                                                          size_t pstride,
                                                          const float* __restrict__ bias,
                                                          float* __restrict__ out) {
  const size_t i = ((size_t)blockIdx.x * 256 + threadIdx.x) * 4;
  const int col = (int)(i % VV);
  const float4 c = *(const float4*)&bias[col];
  float4 o = c;
#pragma unroll
  for (int s = 0; s < KSP; ++s) {
    const float4 a = *(const float4*)&P[s * pstride + i];
    o.x += a.x; o.y += a.y; o.z += a.z; o.w += a.w;
  }
  *(float4*)&out[i] = o;
}

// ---------------- launch ----------------
extern "C" void kernel_launch(void* const* d_in, const int* in_sizes, int n_in,
                              void* d_out, int out_size, void* d_ws, size_t ws_size,
                              hipStream_t stream) {
  const int*   bytes    = (const int*)d_in[0];
  const float* emb      = (const float*)d_in[1];
  const float* alpha    = (const float*)d_in[2];
  const float* enc_inw  = (const float*)d_in[3];
  const float* enc_inb  = (const float*)d_in[4];
  const float* enc_ow   = (const float*)d_in[5];
  const float* enc_ob   = (const float*)d_in[6];
  const float* enc_w1   = (const float*)d_in[7];
  const float* enc_b1   = (const float*)d_in[8];
  const float* enc_w2   = (const float*)d_in[9];
  const float* enc_b2   = (const float*)d_in[10];
  const float* enc_ln1w = (const float*)d_in[11];
  const float* enc_ln1b = (const float*)d_in[12];
  const float* enc_ln2w = (const float*)d_in[13];
  const float* enc_ln2b = (const float*)d_in[14];
  const float* dec_sa_inw = (const float*)d_in[15];
  const float* dec_sa_inb = (const float*)d_in[16];
  const float* dec_sa_ow  = (const float*)d_in[17];
  const float* dec_sa_ob  = (const float*)d_in[18];
  const float* dec_ca_inw = (const float*)d_in[19];
  const float* dec_ca_inb = (const float*)d_in[20];
  const float* dec_ca_ow  = (const float*)d_in[21];
  const float* dec_ca_ob  = (const float*)d_in[22];
  const float* dec_w1   = (const float*)d_in[23];
  const float* dec_b1   = (const float*)d_in[24];
  const float* dec_w2   = (const float*)d_in[25];
  const float* dec_b2   = (const float*)d_in[26];
  const float* dec_ln1w = (const float*)d_in[27];
  const float* dec_ln1b = (const float*)d_in[28];
  const float* dec_ln2w = (const float*)d_in[29];
  const float* dec_ln2b = (const float*)d_in[30];
  const float* dec_ln3w = (const float*)d_in[31];
  const float* dec_ln3b = (const float*)d_in[32];
  const float* out_w    = (const float*)d_in[33];
  const float* out_b    = (const float*)d_in[34];

  // ---- workspace layout ----
  float* fp = (float*)d_ws;
  float* tok   = fp;  fp += (size_t)PP * DD;
  float* stats = fp;  fp += (size_t)NS * PP * HN * 2;
  float* outP  = fp;  fp += (size_t)KSP * PP * VV;
  float* bcbuf = fp;  fp += (size_t)LL * DD;
  short* sp = (short*)fp;
  short* OpartB  = sp;  sp += (size_t)NS * PP * DD;
  short* tmpB    = sp;  sp += (size_t)KSP * PP * DD;
  short* x_bf    = sp;  sp += (size_t)PP * DD;
  short* enc_bf  = sp;  sp += (size_t)PP * DD;
  short* qkv_bf  = sp;  sp += (size_t)PP * 3 * DD;
  short* attno_bf= sp;  sp += (size_t)PP * DD;
  short* ffh_bf  = sp;  sp += (size_t)PP * DFF_;
  short* wvT     = sp;  sp += (size_t)LL * DD * DD;
  short* wcM     = sp;  sp += (size_t)LL * DD * DD;
  short* warena  = sp;

  // ---- weight arena offsets + one-shot convert ----
  CvtArgs ca;
  size_t eoff[LL][4], doff[LL][5], ooff;
  size_t dec_start = 0, dec_stride = 0;
  {
    int si = 0;
    size_t off = 0;
    const size_t n0 = 3 * DD * DD, n1 = DD * DD, n2 = (size_t)DFF_ * DD, n3 = (size_t)DD * DFF_;
    for (int l = 0; l < LL; ++l) {
      ca.seg[si++] = {enc_inw + (size_t)l * n0, warena + off, (int)n0}; eoff[l][0] = off; off += n0;
      ca.seg[si++] = {enc_ow  + (size_t)l * n1, warena + off, (int)n1}; eoff[l][1] = off; off += n1;
      ca.seg[si++] = {enc_w1  + (size_t)l * n2, warena + off, (int)n2}; eoff[l][2] = off; off += n2;
      ca.seg[si++] = {enc_w2  + (size_t)l * n3, warena + off, (int)n3}; eoff[l][3] = off; off += n3;
    }
    dec_start = off;
    for (int l = 0; l < LL; ++l) {
      const size_t o0 = off;
      ca.seg[si++] = {dec_sa_ow  + (size_t)l * n1, warena + off, (int)n1}; doff[l][0] = off; off += n1;
      ca.seg[si++] = {dec_ca_inw + (size_t)l * n0, warena + off, (int)n0}; doff[l][1] = off; off += n0;
      ca.seg[si++] = {dec_ca_ow  + (size_t)l * n1, warena + off, (int)n1}; doff[l][2] = off; off += n1;
      ca.seg[si++] = {dec_w1     + (size_t)l * n2, warena + off, (int)n2}; doff[l][3] = off; off += n2;
      ca.seg[si++] = {dec_w2     + (size_t)l * n3, warena + off, (int)n3}; doff[l][4] = off; off += n3;
      if (l == 0) dec_stride = off - o0; (void)o0;
    }
    ca.seg[si++] = {out_w, warena + off, VV * DD}; ooff = off;
  }

  const dim3 b256(256);
  const dim3 gFA(PP / 64, HN, NS);                 // 32x8x8 = 2048
  const dim3 gQKV(3 * DD / 64, PP / 128);
  const dim3 gFF1(DFF_ / 64, PP / 128);
  const dim3 gS(DD / 64, PP / 64, KSP);            // splitK2: 8x32x2=512
  const dim3 gCA(24, PP / 64);
  const dim3 gOUTg(VV / 64, PP / 64, KSP);
  const size_t psD = (size_t)PP * DD;
  const size_t psV = (size_t)PP * VV;

  // prologue
  convert_bf16_kernel<<<dim3(256, NSEG), b256, 0, stream>>>(ca);
  transpose_wv_kernel<<<dim3(8, 8, LL), b256, 0, stream>>>(dec_sa_inw, wvT);
  sa_bias_kernel<<<(LL * DD) / 4, b256, 0, stream>>>(dec_sa_inb, dec_sa_ow, dec_sa_ob, bcbuf);
  gemm_wc_kernel<<<dim3(8, 8, LL), b256, 0, stream>>>(warena + dec_start, dec_stride, wvT, wcM);
  embed_mean_kernel<<<PP, b256, 0, stream>>>(bytes, emb, x_bf, tok);

  // ---------------- encoder ----------------
  for (int l = 0; l < LL; ++l) {
    const float* inb = enc_inb + (size_t)l * 3 * DD;
    const float* ob  = enc_ob  + (size_t)l * DD;
    const float* b1  = enc_b1  + (size_t)l * DFF_;
    const float* b2  = enc_b2  + (size_t)l * DD;

    gemm_gl_kernel<128, 64, 1, 0, 0, 1, 1><<<gQKV, b256, 0, stream>>>(
        x_bf, DD, warena + eoff[l][0], DD, inb, nullptr, qkv_bf, 3 * DD, DD, 0);
    flash_attn_mfma_kernel<<<gFA, b256, 0, stream>>>(qkv_bf, OpartB, stats);
    attn_combine_kernel<<<PP / 4, b256, 0, stream>>>(OpartB, stats, attno_bf);
    gemm_gl_kernel<64, 64, KSP, 0, 0, 0, 0><<<gS, b256, 0, stream>>>(
        attno_bf, DD, warena + eoff[l][1], DD, nullptr, nullptr, tmpB, DD, DD, psD);
    ln_residual_kernel<<<PP / 4, b256, 0, stream>>>(
        x_bf, tmpB, psD, ob, enc_ln1w + (size_t)l * DD, enc_ln1b + (size_t)l * DD, x_bf);
    gemm_gl_kernel<128, 64, 1, 1, 0, 1, 0><<<gFF1, b256, 0, stream>>>(
        x_bf, DD, warena + eoff[l][2], DD, b1, nullptr, ffh_bf, DFF_, DD, 0);
    gemm_gl_kernel<64, 64, KSP, 0, 0, 0, 0><<<gS, b256, 0, stream>>>(
        ffh_bf, DFF_, warena + eoff[l][3], DFF_, nullptr, nullptr, tmpB, DD, DFF_, psD);
    if (l + 1 < LL) {
      ln_residual_kernel<<<PP / 4, b256, 0, stream>>>(
          x_bf, tmpB, psD, b2, enc_ln2w + (size_t)l * DD, enc_ln2b + (size_t)l * DD, x_bf);
    } else {
      ln_gate_kernel<<<PP / 4, b256, 0, stream>>>(
          x_bf, tmpB, psD, b2, enc_ln2w + (size_t)l * DD, enc_ln2b + (size_t)l * DD,
          tok, alpha, x_bf, enc_bf);
    }
  }

  // ---------------- decoder ----------------
  for (int l = 0; l < LL; ++l) {
    const float* ca_inb = dec_ca_inb + (size_t)l * 3 * DD;
    const float* ca_ob  = dec_ca_ob + (size_t)l * DD;
    const float* b1 = dec_b1 + (size_t)l * DFF_;
    const float* b2 = dec_b2 + (size_t)l * DD;

    gemm_gl_kernel<64, 64, KSP, 0, 0, 0, 0><<<gS, b256, 0, stream>>>(
        x_bf, DD, wcM + (size_t)l * DD * DD, DD, nullptr, nullptr, tmpB, DD, DD, psD);
    ln_residual_kernel<<<PP / 4, b256, 0, stream>>>(
        x_bf, tmpB, psD, bcbuf + (size_t)l * DD,
        dec_ln1w + (size_t)l * DD, dec_ln1b + (size_t)l * DD, x_bf);

    gemm_ca_kernel<<<gCA, b256, 0, stream>>>(
        x_bf, enc_bf, warena + doff[l][1], ca_inb, qkv_bf);
    flash_attn_mfma_kernel<<<gFA, b256, 0, stream>>>(qkv_bf, OpartB, stats);
    attn_combine_kernel<<<PP / 4, b256, 0, stream>>>(OpartB, stats, attno_bf);
    gemm_gl_kernel<64, 64, KSP, 0, 0, 0, 0><<<gS, b256, 0, stream>>>(
        attno_bf, DD, warena + doff[l][2], DD, nullptr, nullptr, tmpB, DD, DD, psD);
    ln_residual_kernel<<<PP / 4, b256, 0, stream>>>(
        x_bf, tmpB, psD, ca_ob, dec_ln2w + (size_t)l * DD, dec_ln2b + (size_t)l * DD, x_bf);

    gemm_gl_kernel<128, 64, 1, 1, 0, 1, 0><<<gFF1, b256, 0, stream>>>(
        x_bf, DD, warena + doff[l][3], DD, b1, nullptr, ffh_bf, DFF_, DD, 0);
    gemm_gl_kernel<64, 64, KSP, 0, 0, 0, 0><<<gS, b256, 0, stream>>>(
        ffh_bf, DFF_, warena + doff[l][4], DFF_, nullptr, nullptr, tmpB, DD, DFF_, psD);
    ln_residual_kernel<<<PP / 4, b256, 0, stream>>>(
        x_bf, tmpB, psD, b2, dec_ln3w + (size_t)l * DD, dec_ln3b + (size_t)l * DD, x_bf);
  }

  // final projection (split-K2, fp32 partials) + combine
  gemm_gl_kernel<64, 64, KSP, 0, 1, 0, 0><<<gOUTg, b256, 0, stream>>>(
      x_bf, DD, warena + ooff, DD, nullptr, outP, nullptr, VV, DD, psV);
  out_combine_kernel<<<(PP * VV / 4) / 256, b256, 0, stream>>>(
      outP, psV, out_b, (float*)d_out);
}

// Round 16
// 965.877 us; speedup vs baseline: 1.0301x; 1.0301x over previous
//
#include <hip/hip_runtime.h>
#include <hip/hip_bf16.h>
#include <math.h>

#define DD   512
#define HN   8
#define DHD  64
#define LL   6
#define DFF_ 2048
#define VV   256
#define KB_  5
#define PP   2048
#define EPS_ 1e-5f
#define TAU_ 0.1f
#define NS   4               // KV splits for flash attention (8 regressed)
#define KVS  (PP / NS)       // 512 keys per split
#define KSP  2               // split-K for small GEMMs (4 regressed)
#define QSCALE 0.18033688f   // 0.125 * log2(e)
#define THRL2  11.5416f

typedef __attribute__((ext_vector_type(8))) short bf16x8;
typedef __attribute__((ext_vector_type(4))) short bf16x4;
typedef __attribute__((ext_vector_type(4))) float f32x4;

// ---------------- helpers ----------------
__device__ __forceinline__ float wave_sum(float v) {
#pragma unroll
  for (int m = 32; m >= 1; m >>= 1) v += __shfl_xor(v, m, 64);
  return v;
}

__device__ __forceinline__ unsigned short f2bf(float f) {
  unsigned u = __float_as_uint(f);
  u += 0x7FFF + ((u >> 16) & 1);
  return (unsigned short)(u >> 16);
}

__device__ __forceinline__ float bf2f(unsigned short u) {
  return __uint_as_float(((unsigned)u) << 16);
}

__device__ __forceinline__ bf16x8 cvt8(float4 a, float4 b) {
  bf16x8 v;
  v[0] = (short)f2bf(a.x); v[1] = (short)f2bf(a.y);
  v[2] = (short)f2bf(a.z); v[3] = (short)f2bf(a.w);
  v[4] = (short)f2bf(b.x); v[5] = (short)f2bf(b.y);
  v[6] = (short)f2bf(b.z); v[7] = (short)f2bf(b.w);
  return v;
}

__device__ __forceinline__ void gload16(const void* g, void* l) {
  __builtin_amdgcn_global_load_lds(
      (const __attribute__((address_space(1))) unsigned int*)g,
      (__attribute__((address_space(3))) unsigned int*)l, 16, 0, 0);
}

// ---------------- batched fp32 -> bf16 convert ----------------
#define NSEG 55
struct CvtSeg { const float* src; short* dst; int n; };
struct CvtArgs { CvtSeg seg[NSEG]; };

__global__ __launch_bounds__(256) void convert_bf16_kernel(CvtArgs a) {
  const CvtSeg sg = a.seg[blockIdx.y];
  const int i = ((int)blockIdx.x * 256 + (int)threadIdx.x) * 16;
  if (i >= sg.n) return;
  const float4 x0 = *(const float4*)(sg.src + i);
  const float4 x1 = *(const float4*)(sg.src + i + 4);
  const float4 x2 = *(const float4*)(sg.src + i + 8);
  const float4 x3 = *(const float4*)(sg.src + i + 12);
  *(bf16x8*)(sg.dst + i)     = cvt8(x0, x1);
  *(bf16x8*)(sg.dst + i + 8) = cvt8(x2, x3);
}

// ---------------- Wv transpose+convert ----------------
__global__ __launch_bounds__(256) void transpose_wv_kernel(const float* __restrict__ sa_inw,
                                                           short* __restrict__ wvt) {
  __shared__ float t[64][65];
  const int l = blockIdx.z;
  const float* S = sa_inw + (size_t)l * 3 * DD * DD + (size_t)2 * DD * DD;
  short* D = wvt + (size_t)l * DD * DD;
  const int bo = blockIdx.y * 64;
  const int bi = blockIdx.x * 64;
  const int r = (int)threadIdx.x >> 2;
  const int c0 = ((int)threadIdx.x & 3) * 16;
#pragma unroll
  for (int j = 0; j < 16; j += 4)
    *(float4*)&t[r][c0 + j] = *(const float4*)&S[(size_t)(bo + r) * DD + bi + c0 + j];
  __syncthreads();
  bf16x8 o0, o1;
#pragma unroll
  for (int j = 0; j < 8; ++j) o0[j] = (short)f2bf(t[c0 + j][r]);
#pragma unroll
  for (int j = 0; j < 8; ++j) o1[j] = (short)f2bf(t[c0 + 8 + j][r]);
  short* dp = &D[(size_t)(bi + r) * DD + bo + c0];
  *(bf16x8*)dp = o0;
  *(bf16x8*)(dp + 8) = o1;
}

// ---------------- sa bias combine ----------------
__global__ __launch_bounds__(256) void sa_bias_kernel(const float* __restrict__ sa_inb,
                                                      const float* __restrict__ sa_ow,
                                                      const float* __restrict__ sa_ob,
                                                      float* __restrict__ bc) {
  const int gid = (int)blockIdx.x * 4 + ((int)threadIdx.x >> 6);
  const int l = gid >> 9, n = gid & 511;
  const int lane = (int)threadIdx.x & 63;
  const float* wo = sa_ow + (size_t)l * DD * DD + (size_t)n * DD + lane * 8;
  const float* bv = sa_inb + (size_t)l * 3 * DD + 2 * DD + lane * 8;
  float s = 0.f;
#pragma unroll
  for (int j = 0; j < 8; ++j) s += wo[j] * bv[j];
  s = wave_sum(s);
  if (lane == 0) bc[(size_t)l * DD + n] = s + sa_ob[(size_t)l * DD + n];
}

// ---------------- batched Wc = Wo @ Wv, 6 layers (BK=64) ----------------
__global__ __launch_bounds__(256) void gemm_wc_kernel(const short* __restrict__ WoBase,
                                                      size_t astr,
                                                      const short* __restrict__ WvT,
                                                      short* __restrict__ Wc) {
  constexpr int BK = 64;
  __shared__ short As[64 * BK];
  __shared__ short Bs[64 * BK];
  const int l = blockIdx.z;
  const short* A = WoBase + (size_t)l * astr;
  const short* W = WvT + (size_t)l * DD * DD;
  short* C = Wc + (size_t)l * DD * DD;
  const int tid = (int)threadIdx.x;
  const int lane = tid & 63;
  const int wid = tid >> 6;
  const int wm = (wid >> 1) * 32;
  const int wn = (wid & 1) * 32;
  const int bm = blockIdx.y * 64;
  const int bn = blockIdx.x * 64;
  const int fr = lane & 15;
  const int kq = lane >> 4;
  const int rs = fr & 7;
  const int srow = lane >> 3;
  const int scg = (lane & 7) ^ srow;

  f32x4 acc[2][2];
#pragma unroll
  for (int i = 0; i < 2; ++i)
#pragma unroll
    for (int j = 0; j < 2; ++j) acc[i][j] = (f32x4){0.f, 0.f, 0.f, 0.f};

  for (int k0 = 0; k0 < DD; k0 += BK) {
    __syncthreads();
#pragma unroll
    for (int is = 0; is < 2; ++is) {
      const int ib = is * 4 + wid;
      gload16(&A[(size_t)(bm + ib * 8 + srow) * DD + k0 + scg * 8], &As[ib * 512]);
      gload16(&W[(size_t)(bn + ib * 8 + srow) * DD + k0 + scg * 8], &Bs[ib * 512]);
    }
    __syncthreads();
#pragma unroll
    for (int s = 0; s < 2; ++s) {
      const int cg = s * 4 + kq;
      const int co = (cg ^ rs) * 8;
      bf16x8 af[2], bf[2];
#pragma unroll
      for (int i = 0; i < 2; ++i) af[i] = *(const bf16x8*)&As[(wm + i * 16 + fr) * BK + co];
#pragma unroll
      for (int j = 0; j < 2; ++j) bf[j] = *(const bf16x8*)&Bs[(wn + j * 16 + fr) * BK + co];
#pragma unroll
      for (int i = 0; i < 2; ++i)
#pragma unroll
        for (int j = 0; j < 2; ++j)
          acc[i][j] = __builtin_amdgcn_mfma_f32_16x16x32_bf16(af[i], bf[j], acc[i][j], 0, 0, 0);
    }
  }
  const int cr = (lane >> 4) * 4;
#pragma unroll
  for (int j = 0; j < 2; ++j) {
    const int col = bn + wn + j * 16 + fr;
#pragma unroll
    for (int i = 0; i < 2; ++i)
#pragma unroll
      for (int r = 0; r < 4; ++r)
        C[(size_t)(bm + wm + i * 16 + cr + r) * DD + col] = (short)f2bf(acc[i][j][r]);
  }
}

// ---------------- embedding (bf16 x master) ----------------
__global__ __launch_bounds__(256) void embed_mean_kernel(const int* __restrict__ bytes,
                                                         const float* __restrict__ emb,
                                                         short* __restrict__ xb,
                                                         float* __restrict__ tok) {
  const int p = blockIdx.x;
  const int d = threadIdx.x * 2;
  float a0 = 0.f, a1 = 0.f;
  int last = 0;
#pragma unroll
  for (int k = 0; k < KB_; ++k) {
    const int idx = bytes[p * KB_ + k];
    last = idx;
    const float* e = emb + (size_t)idx * DD + d;
    a0 += e[0]; a1 += e[1];
  }
  xb[(size_t)p * DD + d]     = (short)f2bf(a0 * 0.2f);
  xb[(size_t)p * DD + d + 1] = (short)f2bf(a1 * 0.2f);
  const float* e = emb + (size_t)last * DD + d;
  tok[(size_t)p * DD + d]     = e[0];
  tok[(size_t)p * DD + d + 1] = e[1];
}

// ---------------- MFMA GEMM, BK=128, gload_lds + XOR swizzle ----------------
template <int BM, int BN, int NSPLIT, int RELU, int WF32, int WBF16, int QS>
__global__ __launch_bounds__(256) void gemm_gl_kernel(
    const short* __restrict__ A, int lda,
    const short* __restrict__ W, int ldw,
    const float* __restrict__ bias,
    float* __restrict__ Cf, short* __restrict__ Cb, int ldc, int Kd,
    size_t pstride) {
  constexpr int BK = 128;
  __shared__ short As[BM * BK];
  __shared__ short Bs[BN * BK];
  constexpr int WM = BM / 2, WN = BN / 2;
  constexpr int MF = WM / 16, NF = WN / 16;
  const int tid = (int)threadIdx.x;
  const int lane = tid & 63;
  const int wid = tid >> 6;
  const int wm = (wid >> 1) * WM;
  const int wn = (wid & 1) * WN;
  const int bm = blockIdx.y * BM;
  const int bn = blockIdx.x * BN;
  const int fr = lane & 15;
  const int kq = lane >> 4;
  const int srow = lane >> 4;
  const int sc16 = lane & 15;

  const int kz = (NSPLIT > 1) ? (int)blockIdx.z : 0;
  const int kbeg = kz * (Kd / NSPLIT);
  const int kend = kbeg + Kd / NSPLIT;

  f32x4 acc[MF][NF];
#pragma unroll
  for (int i = 0; i < MF; ++i)
#pragma unroll
    for (int j = 0; j < NF; ++j) acc[i][j] = (f32x4){0.f, 0.f, 0.f, 0.f};

  for (int k0 = kbeg; k0 < kend; k0 += BK) {
    __syncthreads();
#pragma unroll
    for (int is = 0; is < BM / 16; ++is) {
      const int ib = is * 4 + wid;
      const int row = ib * 4 + srow;
      const int cg = sc16 ^ (row & 15);
      gload16(&A[(size_t)(bm + row) * lda + k0 + cg * 8], &As[ib * 512]);
    }
#pragma unroll
    for (int is = 0; is < BN / 16; ++is) {
      const int ib = is * 4 + wid;
      const int row = ib * 4 + srow;
      const int cg = sc16 ^ (row & 15);
      gload16(&W[(size_t)(bn + row) * ldw + k0 + cg * 8], &Bs[ib * 512]);
    }
    __syncthreads();
#pragma unroll
    for (int s = 0; s < 4; ++s) {
      const int co = ((s * 4 + kq) ^ fr) * 8;
      bf16x8 af[MF], bf[NF];
#pragma unroll
      for (int i = 0; i < MF; ++i)
        af[i] = *(const bf16x8*)&As[(wm + i * 16 + fr) * BK + co];
#pragma unroll
      for (int j = 0; j < NF; ++j)
        bf[j] = *(const bf16x8*)&Bs[(wn + j * 16 + fr) * BK + co];
#pragma unroll
      for (int i = 0; i < MF; ++i)
#pragma unroll
        for (int j = 0; j < NF; ++j)
          acc[i][j] = __builtin_amdgcn_mfma_f32_16x16x32_bf16(af[i], bf[j], acc[i][j], 0, 0, 0);
    }
  }

  const int cr = (lane >> 4) * 4;
  if constexpr (NSPLIT > 1) {
#pragma unroll
    for (int j = 0; j < NF; ++j) {
      const int col = bn + wn + j * 16 + fr;
#pragma unroll
      for (int i = 0; i < MF; ++i)
#pragma unroll
        for (int r = 0; r < 4; ++r) {
          const size_t idx = (size_t)(bm + wm + i * 16 + cr + r) * ldc + col;
          if (WF32) Cf[(size_t)kz * pstride + idx] = acc[i][j][r];
          else      Cb[(size_t)kz * pstride + idx] = (short)f2bf(acc[i][j][r]);
        }
    }
  } else {
#pragma unroll
    for (int j = 0; j < NF; ++j) {
      const int col = bn + wn + j * 16 + fr;
      const float bb = bias[col];
      const float sc = (QS && col < DD) ? QSCALE : 1.f;
#pragma unroll
      for (int i = 0; i < MF; ++i) {
#pragma unroll
        for (int r = 0; r < 4; ++r) {
          float v = (acc[i][j][r] + bb) * sc;
          if (RELU) v = fmaxf(v, 0.f);
          const size_t idx = (size_t)(bm + wm + i * 16 + cr + r) * ldc + col;
          if (WF32) Cf[idx] = v;
          if (WBF16) Cb[idx] = (short)f2bf(v);
        }
      }
    }
  }
}

// ---------------- merged decoder cross-attn projections, BK=128 ----------------
__global__ __launch_bounds__(256) void gemm_ca_kernel(
    const short* __restrict__ Aq, const short* __restrict__ Akv,
    const short* __restrict__ Wfull, const float* __restrict__ bias,
    short* __restrict__ Cb) {
  constexpr int BK = 128;
  __shared__ short As[64 * BK];
  __shared__ short Bs[64 * BK];
  const int bx = (int)blockIdx.x;
  const int part_kv = bx >= 8;
  const short* A = part_kv ? Akv : Aq;
  const int wrow0 = part_kv ? DD + (bx - 8) * 64 : bx * 64;
  const float sc = part_kv ? 1.f : QSCALE;
  const int tid = (int)threadIdx.x;
  const int lane = tid & 63;
  const int wid = tid >> 6;
  const int wm = (wid >> 1) * 32;
  const int wn = (wid & 1) * 32;
  const int bm = blockIdx.y * 64;
  const int fr = lane & 15;
  const int kq = lane >> 4;
  const int srow = lane >> 4;
  const int sc16 = lane & 15;

  f32x4 acc[2][2];
#pragma unroll
  for (int i = 0; i < 2; ++i)
#pragma unroll
    for (int j = 0; j < 2; ++j) acc[i][j] = (f32x4){0.f, 0.f, 0.f, 0.f};

  for (int k0 = 0; k0 < DD; k0 += BK) {
    __syncthreads();
#pragma unroll
    for (int is = 0; is < 4; ++is) {
      const int ib = is * 4 + wid;
      const int row = ib * 4 + srow;
      const int cg = sc16 ^ (row & 15);
      gload16(&A[(size_t)(bm + row) * DD + k0 + cg * 8], &As[ib * 512]);
    }
#pragma unroll
    for (int is = 0; is < 4; ++is) {
      const int ib = is * 4 + wid;
      const int row = ib * 4 + srow;
      const int cg = sc16 ^ (row & 15);
      gload16(&Wfull[(size_t)(wrow0 + row) * DD + k0 + cg * 8], &Bs[ib * 512]);
    }
    __syncthreads();
#pragma unroll
    for (int s = 0; s < 4; ++s) {
      const int co = ((s * 4 + kq) ^ fr) * 8;
      bf16x8 af[2], bf[2];
#pragma unroll
      for (int i = 0; i < 2; ++i) af[i] = *(const bf16x8*)&As[(wm + i * 16 + fr) * BK + co];
#pragma unroll
      for (int j = 0; j < 2; ++j) bf[j] = *(const bf16x8*)&Bs[(wn + j * 16 + fr) * BK + co];
#pragma unroll
      for (int i = 0; i < 2; ++i)
#pragma unroll
        for (int j = 0; j < 2; ++j)
          acc[i][j] = __builtin_amdgcn_mfma_f32_16x16x32_bf16(af[i], bf[j], acc[i][j], 0, 0, 0);
    }
  }
  const int cr = (lane >> 4) * 4;
#pragma unroll
  for (int j = 0; j < 2; ++j) {
    const int col = wrow0 + wn + j * 16 + fr;
    const float bb = bias[col];
#pragma unroll
    for (int i = 0; i < 2; ++i)
#pragma unroll
      for (int r = 0; r < 4; ++r)
        Cb[(size_t)(bm + wm + i * 16 + cr + r) * (3 * DD) + col] =
            (short)f2bf((acc[i][j][r] + bb) * sc);
  }
}

// ---------------- MFMA flash attention (swapped QK^T, exp2, defer-max) ----------------
__global__ __launch_bounds__(256) void flash_attn_mfma_kernel(const short* __restrict__ qkvb,
                                                              short* __restrict__ Opart,
                                                              float* __restrict__ stats) {
  constexpr int LS = 72;
  __shared__ short Ks[64 * 64];
  __shared__ short Vt[64 * LS];
  __shared__ short Ps[64 * LS];
  const int h = blockIdx.y;
  const int q0 = blockIdx.x * 64;
  const int sp = blockIdx.z;
  const int tid = (int)threadIdx.x;
  const int lane = tid & 63;
  const int wid = tid >> 6;
  const int fr = lane & 15;
  const int g = lane >> 4;
  const int kg = g * 8;
  const int rs3 = fr & 7;

  bf16x8 qf[2];
  {
    const short* src = qkvb + (size_t)(q0 + wid * 16 + fr) * (3 * DD) + h * DHD + kg;
    qf[0] = *(const bf16x8*)src;
    qf[1] = *(const bf16x8*)(src + 32);
  }

  f32x4 acc_o[4];
#pragma unroll
  for (int df = 0; df < 4; ++df) acc_o[df] = (f32x4){0.f, 0.f, 0.f, 0.f};
  float mreg = -INFINITY, lsum = 0.f;

  const int srow8 = lane >> 3;
  const int sscg = (lane & 7) ^ srow8;
  const int vk2 = (tid & 31) * 2;
  const int vd8 = (tid >> 5) * 8;

  for (int t = 0; t < KVS / 64; ++t) {
    const int k0 = sp * KVS + t * 64;
    __syncthreads();
    {
#pragma unroll
      for (int p = 0; p < 2; ++p) {
        const int rb = p * 32 + wid * 8;
        gload16(&qkvb[(size_t)(k0 + rb + srow8) * (3 * DD) + DD + h * DHD + sscg * 8],
                &Ks[rb * 64]);
      }
      const short* vbase = qkvb + (size_t)(k0 + vk2) * (3 * DD) + 2 * DD + h * DHD + vd8;
      const bf16x8 v0 = *(const bf16x8*)vbase;
      const bf16x8 v1 = *(const bf16x8*)(vbase + 3 * DD);
#pragma unroll
      for (int j = 0; j < 8; ++j) {
        const unsigned pk = ((unsigned)(unsigned short)v0[j]) |
                            (((unsigned)(unsigned short)v1[j]) << 16);
        *(unsigned*)&Vt[(vd8 + j) * LS + vk2] = pk;
      }
    }
    __syncthreads();

    f32x4 st[4];
#pragma unroll
    for (int nf = 0; nf < 4; ++nf) st[nf] = (f32x4){0.f, 0.f, 0.f, 0.f};
    __builtin_amdgcn_s_setprio(1);
#pragma unroll
    for (int nf = 0; nf < 4; ++nf) {
      const int krow = (nf * 16 + fr) * 64;
      const bf16x8 kf0 = *(const bf16x8*)&Ks[krow + ((g ^ rs3) * 8)];
      const bf16x8 kf1 = *(const bf16x8*)&Ks[krow + (((g + 4) ^ rs3) * 8)];
      st[nf] = __builtin_amdgcn_mfma_f32_16x16x32_bf16(kf0, qf[0], st[nf], 0, 0, 0);
      st[nf] = __builtin_amdgcn_mfma_f32_16x16x32_bf16(kf1, qf[1], st[nf], 0, 0, 0);
    }
    __builtin_amdgcn_s_setprio(0);

    float mx = st[0][0];
#pragma unroll
    for (int nf = 0; nf < 4; ++nf)
#pragma unroll
      for (int i = 0; i < 4; ++i) mx = fmaxf(mx, st[nf][i]);
    mx = fmaxf(mx, __shfl_xor(mx, 16, 64));
    mx = fmaxf(mx, __shfl_xor(mx, 32, 64));

    if (!__all(mx <= mreg + THRL2)) {
      const float mn = fmaxf(mreg, mx);
      const float corr = exp2f(mreg - mn);
      mreg = mn;
      lsum *= corr;
      float corr_acc[4];
#pragma unroll
      for (int i = 0; i < 4; ++i)
        corr_acc[i] = __shfl(corr, (lane & 48) | (g * 4 + i), 64);
#pragma unroll
      for (int df = 0; df < 4; ++df) {
        acc_o[df][0] *= corr_acc[0]; acc_o[df][1] *= corr_acc[1];
        acc_o[df][2] *= corr_acc[2]; acc_o[df][3] *= corr_acc[3];
      }
    }

    float pv[4][4];
    float sum = 0.f;
#pragma unroll
    for (int nf = 0; nf < 4; ++nf)
#pragma unroll
      for (int i = 0; i < 4; ++i) {
        pv[nf][i] = exp2f(st[nf][i] - mreg);
        sum += pv[nf][i];
      }
    sum += __shfl_xor(sum, 16, 64);
    sum += __shfl_xor(sum, 32, 64);
    lsum += sum;

#pragma unroll
    for (int nf = 0; nf < 4; ++nf) {
      bf16x4 pw;
#pragma unroll
      for (int i = 0; i < 4; ++i) pw[i] = (short)f2bf(pv[nf][i]);
      *(bf16x4*)&Ps[(wid * 16 + fr) * LS + nf * 16 + g * 4] = pw;
    }
    asm volatile("s_waitcnt lgkmcnt(0)" ::: "memory");

    const bf16x8 pa0 = *(const bf16x8*)&Ps[(wid * 16 + fr) * LS + kg];
    const bf16x8 pa1 = *(const bf16x8*)&Ps[(wid * 16 + fr) * LS + kg + 32];
    __builtin_amdgcn_s_setprio(1);
#pragma unroll
    for (int df = 0; df < 4; ++df) {
      const bf16x8 vb0 = *(const bf16x8*)&Vt[(df * 16 + fr) * LS + kg];
      const bf16x8 vb1 = *(const bf16x8*)&Vt[(df * 16 + fr) * LS + kg + 32];
      acc_o[df] = __builtin_amdgcn_mfma_f32_16x16x32_bf16(pa0, vb0, acc_o[df], 0, 0, 0);
      acc_o[df] = __builtin_amdgcn_mfma_f32_16x16x32_bf16(pa1, vb1, acc_o[df], 0, 0, 0);
    }
    __builtin_amdgcn_s_setprio(0);
  }

  const int orow = q0 + wid * 16 + g * 4;
#pragma unroll
  for (int df = 0; df < 4; ++df)
#pragma unroll
    for (int i = 0; i < 4; ++i)
      Opart[((size_t)sp * PP + orow + i) * DD + h * DHD + df * 16 + fr] =
          (short)f2bf(acc_o[df][i]);
  if (g == 0) {
    const size_t si = (((size_t)sp * PP + q0 + wid * 16 + fr) * HN + h) * 2;
    stats[si]     = mreg;
    stats[si + 1] = lsum;
  }
}

// ---------------- combine NS bf16 partials -> attno bf16 ----------------
__global__ __launch_bounds__(256) void attn_combine_kernel(const short* __restrict__ Opart,
                                                           const float* __restrict__ stats,
                                                           short* __restrict__ outb) {
  const int row = blockIdx.x * 4 + ((int)threadIdx.x >> 6);
  const int lane = (int)threadIdx.x & 63;
  const int d0 = lane * 8;
  const int h = d0 >> 6;
  float m[NS], l[NS];
  float M = -INFINITY;
#pragma unroll
  for (int s = 0; s < NS; ++s) {
    const size_t si = (((size_t)s * PP + row) * HN + h) * 2;
    m[s] = stats[si]; l[s] = stats[si + 1];
    M = fmaxf(M, m[s]);
  }
  float L = 0.f;
  float o[8];
#pragma unroll
  for (int j = 0; j < 8; ++j) o[j] = 0.f;
#pragma unroll
  for (int s = 0; s < NS; ++s) {
    const float e = exp2f(m[s] - M);
    L += l[s] * e;
    const bf16x8 v = *(const bf16x8*)&Opart[((size_t)s * PP + row) * DD + d0];
#pragma unroll
    for (int j = 0; j < 8; ++j) o[j] += bf2f((unsigned short)v[j]) * e;
  }
  const float inv = 1.f / L;
  bf16x8 ob;
#pragma unroll
  for (int j = 0; j < 8; ++j) ob[j] = (short)f2bf(o[j] * inv);
  *(bf16x8*)&outb[(size_t)row * DD + d0] = ob;
}

// ---------------- LN(x + ΣP + gbias) * w + b -> bf16 ----------------
__global__ __launch_bounds__(256) void ln_residual_kernel(const short* __restrict__ xin,
                                                          const short* __restrict__ pP,
                                                          size_t pstride,
                                                          const float* __restrict__ gb,
                                                          const float* __restrict__ w,
                                                          const float* __restrict__ b,
                                                          short* __restrict__ outb) {
  const int row = blockIdx.x * 4 + (threadIdx.x >> 6);
  const int lane = threadIdx.x & 63;
  const size_t base = (size_t)row * DD + lane * 8;
  float v[8];
  {
    const bf16x8 a = *(const bf16x8*)&xin[base];
    const float4 g0 = *(const float4*)&gb[lane * 8];
    const float4 g1 = *(const float4*)&gb[lane * 8 + 4];
    const float gg[8] = {g0.x, g0.y, g0.z, g0.w, g1.x, g1.y, g1.z, g1.w};
#pragma unroll
    for (int j = 0; j < 8; ++j) v[j] = bf2f((unsigned short)a[j]) + gg[j];
#pragma unroll
    for (int s = 0; s < KSP; ++s) {
      const bf16x8 p = *(const bf16x8*)&pP[s * pstride + base];
#pragma unroll
      for (int j = 0; j < 8; ++j) v[j] += bf2f((unsigned short)p[j]);
    }
  }
  float sum = 0.f;
#pragma unroll
  for (int j = 0; j < 8; ++j) sum += v[j];
  sum = wave_sum(sum);
  const float mean = sum * (1.f / DD);
  float sq = 0.f;
#pragma unroll
  for (int j = 0; j < 8; ++j) { const float dd = v[j] - mean; sq += dd * dd; }
  sq = wave_sum(sq);
  const float rstd = rsqrtf(sq * (1.f / DD) + EPS_);
  const float* wp = w + lane * 8;
  const float* bp = b + lane * 8;
  bf16x8 ob;
#pragma unroll
  for (int j = 0; j < 8; ++j)
    ob[j] = (short)f2bf((v[j] - mean) * rstd * wp[j] + bp[j]);
  *(bf16x8*)&outb[base] = ob;
}

// ---------------- final encoder LN fused with gate+mix ----------------
__global__ __launch_bounds__(256) void ln_gate_kernel(const short* __restrict__ xin,
                                                      const short* __restrict__ pP,
                                                      size_t pstride,
                                                      const float* __restrict__ gb,
                                                      const float* __restrict__ w,
                                                      const float* __restrict__ b,
                                                      const float* __restrict__ tok,
                                                      const float* __restrict__ alpha_p,
                                                      short* __restrict__ xb,
                                                      short* __restrict__ encb) {
  const int row = blockIdx.x * 4 + (threadIdx.x >> 6);
  const int lane = threadIdx.x & 63;
  const size_t base = (size_t)row * DD + lane * 8;
  float v[8];
  {
    const bf16x8 a = *(const bf16x8*)&xin[base];
    const float4 g0 = *(const float4*)&gb[lane * 8];
    const float4 g1 = *(const float4*)&gb[lane * 8 + 4];
    const float gg[8] = {g0.x, g0.y, g0.z, g0.w, g1.x, g1.y, g1.z, g1.w};
#pragma unroll
    for (int j = 0; j < 8; ++j) v[j] = bf2f((unsigned short)a[j]) + gg[j];
#pragma unroll
    for (int s = 0; s < KSP; ++s) {
      const bf16x8 p = *(const bf16x8*)&pP[s * pstride + base];
#pragma unroll
      for (int j = 0; j < 8; ++j) v[j] += bf2f((unsigned short)p[j]);
    }
  }
  float sum = 0.f;
#pragma unroll
  for (int j = 0; j < 8; ++j) sum += v[j];
  sum = wave_sum(sum);
  const float mean = sum * (1.f / DD);
  float sq = 0.f;
#pragma unroll
  for (int j = 0; j < 8; ++j) { const float dd = v[j] - mean; sq += dd * dd; }
  sq = wave_sum(sq);
  const float rstd = rsqrtf(sq * (1.f / DD) + EPS_);
  const float* wp = w + lane * 8;
  const float* bp = b + lane * 8;
  float e[8];
#pragma unroll
  for (int j = 0; j < 8; ++j) e[j] = (v[j] - mean) * rstd * wp[j] + bp[j];
  bf16x8 eb;
#pragma unroll
  for (int j = 0; j < 8; ++j) eb[j] = (short)f2bf(e[j]);
  *(bf16x8*)&encb[base] = eb;
  float nsq = 0.f;
#pragma unroll
  for (int j = 0; j < 8; ++j) nsq += e[j] * e[j];
  nsq = wave_sum(nsq);
  const bool gate = nsq > TAU_ * TAU_;
  const float a = *alpha_p;
  float t[8];
  {
    const float4 b0 = *(const float4*)&tok[base];
    const float4 b1 = *(const float4*)&tok[base + 4];
    t[0] = b0.x; t[1] = b0.y; t[2] = b0.z; t[3] = b0.w;
    t[4] = b1.x; t[5] = b1.y; t[6] = b1.z; t[7] = b1.w;
  }
  bf16x8 ob;
#pragma unroll
  for (int j = 0; j < 8; ++j)
    ob[j] = (short)f2bf(gate ? (a * e[j] + (1.f - a) * t[j]) : t[j]);
  *(bf16x8*)&xb[base] = ob;
}

// ---------------- final out combine: d_out = ΣP + bias ----------------
__global__ __launch_bounds__(256) void out_combine_kernel(const float* __restrict__ P,
                                                          size_t pstride,
                                                          const float* __restrict__ bias,
                                                          float* __restrict__ out) {
  const size_t i = ((size_t)blockIdx.x * 256 + threadIdx.x) * 4;
  const int col = (int)(i % VV);
  const float4 c = *(const float4*)&bias[col];
  float4 o = c;
#pragma unroll
  for (int s = 0; s < KSP; ++s) {
    const float4 a = *(const float4*)&P[s * pstride + i];
    o.x += a.x; o.y += a.y; o.z += a.z; o.w += a.w;
  }
  *(float4*)&out[i] = o;
}

// ---------------- launch ----------------
extern "C" void kernel_launch(void* const* d_in, const int* in_sizes, int n_in,
                              void* d_out, int out_size, void* d_ws, size_t ws_size,
                              hipStream_t stream) {
  const int*   bytes    = (const int*)d_in[0];
  const float* emb      = (const float*)d_in[1];
  const float* alpha    = (const float*)d_in[2];
  const float* enc_inw  = (const float*)d_in[3];
  const float* enc_inb  = (const float*)d_in[4];
  const float* enc_ow   = (const float*)d_in[5];
  const float* enc_ob   = (const float*)d_in[6];
  const float* enc_w1   = (const float*)d_in[7];
  const float* enc_b1   = (const float*)d_in[8];
  const float* enc_w2   = (const float*)d_in[9];
  const float* enc_b2   = (const float*)d_in[10];
  const float* enc_ln1w = (const float*)d_in[11];
  const float* enc_ln1b = (const float*)d_in[12];
  const float* enc_ln2w = (const float*)d_in[13];
  const float* enc_ln2b = (const float*)d_in[14];
  const float* dec_sa_inw = (const float*)d_in[15];
  const float* dec_sa_inb = (const float*)d_in[16];
  const float* dec_sa_ow  = (const float*)d_in[17];
  const float* dec_sa_ob  = (const float*)d_in[18];
  const float* dec_ca_inw = (const float*)d_in[19];
  const float* dec_ca_inb = (const float*)d_in[20];
  const float* dec_ca_ow  = (const float*)d_in[21];
  const float* dec_ca_ob  = (const float*)d_in[22];
  const float* dec_w1   = (const float*)d_in[23];
  const float* dec_b1   = (const float*)d_in[24];
  const float* dec_w2   = (const float*)d_in[25];
  const float* dec_b2   = (const float*)d_in[26];
  const float* dec_ln1w = (const float*)d_in[27];
  const float* dec_ln1b = (const float*)d_in[28];
  const float* dec_ln2w = (const float*)d_in[29];
  const float* dec_ln2b = (const float*)d_in[30];
  const float* dec_ln3w = (const float*)d_in[31];
  const float* dec_ln3b = (const float*)d_in[32];
  const float* out_w    = (const float*)d_in[33];
  const float* out_b    = (const float*)d_in[34];

  // ---- workspace layout ----
  float* fp = (float*)d_ws;
  float* tok   = fp;  fp += (size_t)PP * DD;
  float* stats = fp;  fp += (size_t)NS * PP * HN * 2;
  float* outP  = fp;  fp += (size_t)KSP * PP * VV;
  float* bcbuf = fp;  fp += (size_t)LL * DD;
  short* sp = (short*)fp;
  short* OpartB  = sp;  sp += (size_t)NS * PP * DD;
  short* tmpB    = sp;  sp += (size_t)KSP * PP * DD;
  short* x_bf    = sp;  sp += (size_t)PP * DD;
  short* enc_bf  = sp;  sp += (size_t)PP * DD;
  short* qkv_bf  = sp;  sp += (size_t)PP * 3 * DD;
  short* attno_bf= sp;  sp += (size_t)PP * DD;
  short* ffh_bf  = sp;  sp += (size_t)PP * DFF_;
  short* wvT     = sp;  sp += (size_t)LL * DD * DD;
  short* wcM     = sp;  sp += (size_t)LL * DD * DD;
  short* warena  = sp;

  // ---- weight arena offsets + one-shot convert ----
  CvtArgs ca;
  size_t eoff[LL][4], doff[LL][5], ooff;
  size_t dec_start = 0, dec_stride = 0;
  {
    int si = 0;
    size_t off = 0;
    const size_t n0 = 3 * DD * DD, n1 = DD * DD, n2 = (size_t)DFF_ * DD, n3 = (size_t)DD * DFF_;
    for (int l = 0; l < LL; ++l) {
      ca.seg[si++] = {enc_inw + (size_t)l * n0, warena + off, (int)n0}; eoff[l][0] = off; off += n0;
      ca.seg[si++] = {enc_ow  + (size_t)l * n1, warena + off, (int)n1}; eoff[l][1] = off; off += n1;
      ca.seg[si++] = {enc_w1  + (size_t)l * n2, warena + off, (int)n2}; eoff[l][2] = off; off += n2;
      ca.seg[si++] = {enc_w2  + (size_t)l * n3, warena + off, (int)n3}; eoff[l][3] = off; off += n3;
    }
    dec_start = off;
    for (int l = 0; l < LL; ++l) {
      const size_t o0 = off;
      ca.seg[si++] = {dec_sa_ow  + (size_t)l * n1, warena + off, (int)n1}; doff[l][0] = off; off += n1;
      ca.seg[si++] = {dec_ca_inw + (size_t)l * n0, warena + off, (int)n0}; doff[l][1] = off; off += n0;
      ca.seg[si++] = {dec_ca_ow  + (size_t)l * n1, warena + off, (int)n1}; doff[l][2] = off; off += n1;
      ca.seg[si++] = {dec_w1     + (size_t)l * n2, warena + off, (int)n2}; doff[l][3] = off; off += n2;
      ca.seg[si++] = {dec_w2     + (size_t)l * n3, warena + off, (int)n3}; doff[l][4] = off; off += n3;
      if (l == 0) dec_stride = off - o0; (void)o0;
    }
    ca.seg[si++] = {out_w, warena + off, VV * DD}; ooff = off;
  }

  const dim3 b256(256);
  const dim3 gFA(PP / 64, HN, NS);                 // 32x8x4 = 1024
  const dim3 gQKV(3 * DD / 64, PP / 128);
  const dim3 gFF1(DFF_ / 64, PP / 128);
  const dim3 gS(DD / 64, PP / 64, KSP);            // splitK2: 8x32x2=512
  const dim3 gCA(24, PP / 64);
  const dim3 gOUTg(VV / 64, PP / 64, KSP);
  const size_t psD = (size_t)PP * DD;
  const size_t psV = (size_t)PP * VV;

  // prologue
  convert_bf16_kernel<<<dim3(256, NSEG), b256, 0, stream>>>(ca);
  transpose_wv_kernel<<<dim3(8, 8, LL), b256, 0, stream>>>(dec_sa_inw, wvT);
  sa_bias_kernel<<<(LL * DD) / 4, b256, 0, stream>>>(dec_sa_inb, dec_sa_ow, dec_sa_ob, bcbuf);
  gemm_wc_kernel<<<dim3(8, 8, LL), b256, 0, stream>>>(warena + dec_start, dec_stride, wvT, wcM);
  embed_mean_kernel<<<PP, b256, 0, stream>>>(bytes, emb, x_bf, tok);

  // ---------------- encoder ----------------
  for (int l = 0; l < LL; ++l) {
    const float* inb = enc_inb + (size_t)l * 3 * DD;
    const float* ob  = enc_ob  + (size_t)l * DD;
    const float* b1  = enc_b1  + (size_t)l * DFF_;
    const float* b2  = enc_b2  + (size_t)l * DD;

    gemm_gl_kernel<128, 64, 1, 0, 0, 1, 1><<<gQKV, b256, 0, stream>>>(
        x_bf, DD, warena + eoff[l][0], DD, inb, nullptr, qkv_bf, 3 * DD, DD, 0);
    flash_attn_mfma_kernel<<<gFA, b256, 0, stream>>>(qkv_bf, OpartB, stats);
    attn_combine_kernel<<<PP / 4, b256, 0, stream>>>(OpartB, stats, attno_bf);
    gemm_gl_kernel<64, 64, KSP, 0, 0, 0, 0><<<gS, b256, 0, stream>>>(
        attno_bf, DD, warena + eoff[l][1], DD, nullptr, nullptr, tmpB, DD, DD, psD);
    ln_residual_kernel<<<PP / 4, b256, 0, stream>>>(
        x_bf, tmpB, psD, ob, enc_ln1w + (size_t)l * DD, enc_ln1b + (size_t)l * DD, x_bf);
    gemm_gl_kernel<128, 64, 1, 1, 0, 1, 0><<<gFF1, b256, 0, stream>>>(
        x_bf, DD, warena + eoff[l][2], DD, b1, nullptr, ffh_bf, DFF_, DD, 0);
    gemm_gl_kernel<64, 64, KSP, 0, 0, 0, 0><<<gS, b256, 0, stream>>>(
        ffh_bf, DFF_, warena + eoff[l][3], DFF_, nullptr, nullptr, tmpB, DD, DFF_, psD);
    if (l + 1 < LL) {
      ln_residual_kernel<<<PP / 4, b256, 0, stream>>>(
          x_bf, tmpB, psD, b2, enc_ln2w + (size_t)l * DD, enc_ln2b + (size_t)l * DD, x_bf);
    } else {
      ln_gate_kernel<<<PP / 4, b256, 0, stream>>>(
          x_bf, tmpB, psD, b2, enc_ln2w + (size_t)l * DD, enc_ln2b + (size_t)l * DD,
          tok, alpha, x_bf, enc_bf);
    }
  }

  // ---------------- decoder ----------------
  for (int l = 0; l < LL; ++l) {
    const float* ca_inb = dec_ca_inb + (size_t)l * 3 * DD;
    const float* ca_ob  = dec_ca_ob + (size_t)l * DD;
    const float* b1 = dec_b1 + (size_t)l * DFF_;
    const float* b2 = dec_b2 + (size_t)l * DD;

    gemm_gl_kernel<64, 64, KSP, 0, 0, 0, 0><<<gS, b256, 0, stream>>>(
        x_bf, DD, wcM + (size_t)l * DD * DD, DD, nullptr, nullptr, tmpB, DD, DD, psD);
    ln_residual_kernel<<<PP / 4, b256, 0, stream>>>(
        x_bf, tmpB, psD, bcbuf + (size_t)l * DD,
        dec_ln1w + (size_t)l * DD, dec_ln1b + (size_t)l * DD, x_bf);

    gemm_ca_kernel<<<gCA, b256, 0, stream>>>(
        x_bf, enc_bf, warena + doff[l][1], ca_inb, qkv_bf);
    flash_attn_mfma_kernel<<<gFA, b256, 0, stream>>>(qkv_bf, OpartB, stats);
    attn_combine_kernel<<<PP / 4, b256, 0, stream>>>(OpartB, stats, attno_bf);
    gemm_gl_kernel<64, 64, KSP, 0, 0, 0, 0><<<gS, b256, 0, stream>>>(
        attno_bf, DD, warena + doff[l][2], DD, nullptr, nullptr, tmpB, DD, DD, psD);
    ln_residual_kernel<<<PP / 4, b256, 0, stream>>>(
        x_bf, tmpB, psD, ca_ob, dec_ln2w + (size_t)l * DD, dec_ln2b + (size_t)l * DD, x_bf);

    gemm_gl_kernel<128, 64, 1, 1, 0, 1, 0><<<gFF1, b256, 0, stream>>>(
        x_bf, DD, warena + doff[l][3], DD, b1, nullptr, ffh_bf, DFF_, DD, 0);
    gemm_gl_kernel<64, 64, KSP, 0, 0, 0, 0><<<gS, b256, 0, stream>>>(
        ffh_bf, DFF_, warena + doff[l][4], DFF_, nullptr, nullptr, tmpB, DD, DFF_, psD);
    ln_residual_kernel<<<PP / 4, b256, 0, stream>>>(
        x_bf, tmpB, psD, b2, dec_ln3w + (size_t)l * DD, dec_ln3b + (size_t)l * DD, x_bf);
  }

  // final projection (split-K2, fp32 partials) + combine
  gemm_gl_kernel<64, 64, KSP, 0, 1, 0, 0><<<gOUTg, b256, 0, stream>>>(
      x_bf, DD, warena + ooff, DD, nullptr, outP, nullptr, VV, DD, psV);
  out_combine_kernel<<<(PP * VV / 4) / 256, b256, 0, stream>>>(
      outP, psV, out_b, (float*)d_out);
}